// Round 8
// baseline (30.079 us; speedup 1.0000x reference)
//
#include <hip/hip_runtime.h>
#include <math.h>

#define NRAYS 32768      // 16*64*32
#define NSPH  1024
#define SUBS  16         // subchunks per ray (64 spheres each)
#define PAIRS 32         // sphere-pairs per subchunk
#define RPB   16         // rays per block
#define TPB   256
#define NBLK  (NRAYS / RPB)   // 2048 blocks

__global__ __launch_bounds__(256, 8) void sphere_kernel(
    const float* __restrict__ rays,
    const float* __restrict__ centers,
    const float* __restrict__ radii,
    float* __restrict__ out)
{
#pragma clang fp contract(off)
    // Pair-SoA: pair p of sub k: sph[base+2p]=(x0,x1,y0,y1), sph[base+2p+1]=(z0,z1,r2_0,r2_1)
    // sub stride 65 float4 = 1040 B -> the 4 broadcast addresses per wave hit
    // disjoint bank quads (conflict-free).
    __shared__ float4 sph[SUBS * (2 * PAIRS + 1)];   // 16.6 KB
    __shared__ float  s_min[SUBS][RPB];
    __shared__ int    s_face[SUBS][RPB];

    const int tid = threadIdx.x;

    for (int p = tid; p < NSPH / 2; p += TPB) {
        const int g0 = 2 * p, g1 = 2 * p + 1;
        const float x0 = centers[3 * g0 + 0], y0 = centers[3 * g0 + 1], z0 = centers[3 * g0 + 2];
        const float x1 = centers[3 * g1 + 0], y1 = centers[3 * g1 + 1], z1 = centers[3 * g1 + 2];
        const float r0 = radii[g0], r1 = radii[g1];
        const int b4 = (p >> 5) * (2 * PAIRS + 1) + (p & 31) * 2;
        sph[b4 + 0] = make_float4(x0, x1, y0, y1);
        sph[b4 + 1] = make_float4(z0, z1, r0 * r0, r1 * r1);
    }
    __syncthreads();

    const int rl  = tid & (RPB - 1);   // ray within block, 0..15
    const int sub = tid >> 4;          // subchunk 0..15
    const int ray = blockIdx.x * RPB + rl;

    const float2* rp = (const float2*)(rays + ray * 6);
    const float2 q0 = rp[0], q1 = rp[1], q2 = rp[2];
    const float ox = q0.x, oy = q0.y, oz = q1.x;
    const float dx = q1.y, dy = q2.x, dz = q2.y;

    // a = ((dx*dx)+(dy*dy))+(dz*dz) -- numpy 3-elem sum order
    const float a       = ((dx * dx) + (dy * dy)) + (dz * dz);
    const float epsA    = 1e-8f * a;       // w >= epsA  <=>  fl(w/a) >= 1e-8
    const float negEpsA = -(1e-8f * a);
    const float hunA    = 100.0f * a;      // deferred: active <=> bw < hunA
    const float INF     = __builtin_inff();

    float cw   = INF;   // numerator of current min t (u = t*a before rounding)
    int   carg = 0;     // argmin within subchunk (first occurrence)

    const float4* __restrict__ spb = &sph[sub * (2 * PAIRS + 1)];

    // Validated 7-op tail (R7): no explicit z>0 test -- v_sqrt(z<0) = NaN,
    // which fails u>=epsA (exact z==0 edge is measure-zero; R7 passed).
#define TEST(SX, SY, SZ, R2, IDX)                                              \
    {                                                                          \
        const float fx = ox - (SX), fy = oy - (SY), fz = oz - (SZ);            \
        const float dt = ((dx * fx) + (dy * fy)) + (dz * fz);                  \
        const float cc = (((fx * fx) + (fy * fy)) + (fz * fz)) - (R2);         \
        const float z  = (dt * dt) - (a * cc);   /* d == 4z, exact scaling */  \
        const float s  = __builtin_amdgcn_sqrtf(z);    /* NaN if z<0 */        \
        const float sum = dt + s;                                              \
        const float w0  = s - dt;                                              \
        const float u   = (sum <= negEpsA) ? -sum : w0;                        \
        const bool  ok  = (u >= epsA) && (u < cw);     /* NaN -> false */      \
        cw   = ok ? u : cw;                                                    \
        carg = ok ? (IDX) : carg;          /* strict <: first occurrence */    \
    }

#pragma unroll 8
    for (int i = 0; i < PAIRS; ++i) {
        const float4 A = spb[2 * i];       // (x0,x1,y0,y1)
        const float4 B = spb[2 * i + 1];   // (z0,z1,r2_0,r2_1)
        TEST(A.x, A.z, B.x, B.z, 2 * i);
        TEST(A.y, A.w, B.y, B.w, 2 * i + 1);
    }
#undef TEST

    s_min[sub][rl]  = cw;
    s_face[sub][rl] = ((sub & 3) << 6) | carg;  // chunk-LOCAL face index (0..255)
    __syncthreads();

    // Epilogue: threads 0..15 handle one ray each.
    if (tid < RPB) {
        float bw   = INF;
        int   face = -1;
        for (int k = 0; k < SUBS; ++k) {
            const float mt = s_min[k][tid];
            if (mt < bw) { bw = mt; face = s_face[k][tid]; }  // earlier chunk wins ties
        }
        // Deferred window test: any in-window u beats every u>=hunA in the min,
        // so bw<hunA <=> reference's any(mask); argmin unaffected.
        const bool active = bw < hunA;

        // Single IEEE division per ray: best = fl(u*/a) == reference's rounded t.
        const float best = active ? (bw / a) : 100.0f;

        float px = ox + (best * dx);
        float py = oy + (best * dy);
        float pz = oz + (best * dz);

        // reference: idx = clip(face,0,1023), face in [-1,255] (chunk-local bug kept)
        const int gidx = face < 0 ? 0 : face;
        const int b4 = (gidx >> 6) * (2 * PAIRS + 1) + ((gidx & 63) >> 1) * 2;
        const int j  = gidx & 1;
        const float4 A = sph[b4];
        const float4 B = sph[b4 + 1];
        const float cxv = j ? A.y : A.x;
        const float cyv = j ? A.w : A.z;
        const float czv = j ? B.y : B.x;
        const float ddx = px - cxv;
        const float ddy = py - cyv;
        const float ddz = pz - czv;
        float nrm = sqrtf(((ddx * ddx) + (ddy * ddy)) + (ddz * ddz));
        nrm = fmaxf(nrm, 1e-12f);
        const float nx = active ? (ddx / nrm) : 0.0f;
        const float ny = active ? (ddy / nrm) : 0.0f;
        const float nz = active ? (ddz / nrm) : 0.0f;
        px = px + (nx * 1e-5f);
        py = py + (ny * 1e-5f);
        pz = pz + (nz * 1e-5f);

        const int r = blockIdx.x * RPB + tid;
        float* outp = out;                 // p: 3*NRAYS
        float* outn = out + NRAYS * 3;     // n: 3*NRAYS
        float* outd = out + NRAYS * 6;     // best_dists: NRAYS
        float* outa = out + NRAYS * 7;     // out_active: NRAYS

        outp[r * 3 + 0] = px;
        outp[r * 3 + 1] = py;
        outp[r * 3 + 2] = pz;
        outn[r * 3 + 0] = nx;
        outn[r * 3 + 1] = ny;
        outn[r * 3 + 2] = nz;
        outd[r] = best;
        outa[r] = active ? 1.0f : 0.0f;
    }
}

extern "C" void kernel_launch(void* const* d_in, const int* in_sizes, int n_in,
                              void* d_out, int out_size, void* d_ws, size_t ws_size,
                              hipStream_t stream) {
    const float* rays    = (const float*)d_in[0];
    const float* centers = (const float*)d_in[1];
    const float* radii   = (const float*)d_in[2];
    float* out = (float*)d_out;

    dim3 grid(NBLK);     // 2048 blocks
    dim3 block(TPB);     // 256 threads
    hipLaunchKernelGGL(sphere_kernel, grid, block, 0, stream,
                       rays, centers, radii, out);
}

// Round 9
// 25.734 us; speedup vs baseline: 1.1689x; 1.1689x over previous
//
#include <hip/hip_runtime.h>
#include <math.h>

#define NRAYS 32768      // 16*64*32
#define NSPH  1024
#define SUBS  16         // subchunks per ray (64 spheres each)
#define PAIRS 32         // sphere-pairs per subchunk
#define RPB   16         // rays per block
#define TPB   256
#define NBLK  (NRAYS / RPB)   // 2048 blocks

typedef float v2f __attribute__((ext_vector_type(2)));

__global__ __launch_bounds__(256, 8) void sphere_kernel(
    const float* __restrict__ rays,
    const float* __restrict__ centers,
    const float* __restrict__ radii,
    float* __restrict__ out)
{
#pragma clang fp contract(off)
    // Pair-SoA: pair p of sub k: sph[base+2p]=(x0,x1,y0,y1), sph[base+2p+1]=(z0,z1,r2_0,r2_1)
    // sub stride 65 float4 = 1040 B -> the 4 broadcast addresses per wave hit
    // disjoint bank quads (conflict-free).
    __shared__ float4 sph[SUBS * (2 * PAIRS + 1)];   // 16.6 KB
    __shared__ float  s_min[SUBS][RPB];
    __shared__ int    s_face[SUBS][RPB];

    const int tid = threadIdx.x;

    for (int p = tid; p < NSPH / 2; p += TPB) {
        const int g0 = 2 * p, g1 = 2 * p + 1;
        const float x0 = centers[3 * g0 + 0], y0 = centers[3 * g0 + 1], z0 = centers[3 * g0 + 2];
        const float x1 = centers[3 * g1 + 0], y1 = centers[3 * g1 + 1], z1 = centers[3 * g1 + 2];
        const float r0 = radii[g0], r1 = radii[g1];
        const int b4 = (p >> 5) * (2 * PAIRS + 1) + (p & 31) * 2;
        sph[b4 + 0] = make_float4(x0, x1, y0, y1);
        sph[b4 + 1] = make_float4(z0, z1, r0 * r0, r1 * r1);
    }
    __syncthreads();

    const int rl  = tid & (RPB - 1);   // ray within block, 0..15
    const int sub = tid >> 4;          // subchunk 0..15
    const int ray = blockIdx.x * RPB + rl;

    const float2* rp = (const float2*)(rays + ray * 6);
    const float2 q0 = rp[0], q1 = rp[1], q2 = rp[2];
    const float ox = q0.x, oy = q0.y, oz = q1.x;
    const float dx = q1.y, dy = q2.x, dz = q2.y;

    // a = ((dx*dx)+(dy*dy))+(dz*dz) -- numpy 3-elem sum order
    const float a    = ((dx * dx) + (dy * dy)) + (dz * dz);
    const float epsA = 1e-8f * a;      // w >= epsA  <=>  fl(w/a) >= 1e-8
    const float hunA = 100.0f * a;     // deferred: active <=> bw < hunA
    const float INF  = __builtin_inff();

    const v2f ox2 = {ox, ox}, oy2 = {oy, oy}, oz2 = {oz, oz};
    const v2f dx2 = {dx, dx}, dy2 = {dy, dy}, dz2 = {dz, dz};
    const v2f a2  = {a, a};

    // Dual accumulators: component 0 = even spheres (2i), component 1 = odd (2i+1).
    float cwE = INF, cwO = INF;
    int   cargE = 0, cargO = 0;   // pair index i of current min

    const float4* __restrict__ spb = &sph[sub * (2 * PAIRS + 1)];

#pragma unroll 8
    for (int i = 0; i < PAIRS; ++i) {
        const float4 A = spb[2 * i];       // (x0,x1,y0,y1)
        const float4 B = spb[2 * i + 1];   // (z0,z1,r2_0,r2_1)
        const v2f X = {A.x, A.y}, Y = {A.z, A.w};
        const v2f Z = {B.x, B.y}, Q = {B.z, B.w};
        const v2f fx = ox2 - X;            // pk-packed front (rounding == scalar)
        const v2f fy = oy2 - Y;
        const v2f fz = oz2 - Z;
        const v2f dt = ((dx2 * fx) + (dy2 * fy)) + (dz2 * fz);   // numpy sum order
        const v2f cc = (((fx * fx) + (fy * fy)) + (fz * fz)) - Q;
        const v2f zz = (dt * dt) - (a2 * cc);   // d == 4*zz, exact pow2 scaling
        const v2f s  = { __builtin_amdgcn_sqrtf(zz.x),   // raw v_sqrt; NaN if z<0
                         __builtin_amdgcn_sqrtf(zz.y) };
        const v2f w0 = s - dt;             // larger-root numerator (pk)
        const v2f w1 = -(dt + s);          // smaller-root numerator (pk, neg folded)
        {   // even sphere 2i -> accumulator E
            const float u  = (w1.x >= epsA) ? w1.x : w0.x;
            const bool ok  = (w0.x >= epsA) & (u < cwE);   // NaN -> false
            cwE   = ok ? u : cwE;
            cargE = ok ? i : cargE;        // strict <: first occurrence
        }
        {   // odd sphere 2i+1 -> accumulator O
            const float u  = (w1.y >= epsA) ? w1.y : w0.y;
            const bool ok  = (w0.y >= epsA) & (u < cwO);
            cwO   = ok ? u : cwO;
            cargO = ok ? i : cargO;
        }
    }

    // Exact merge with first-occurrence tie-break:
    // global idx even = 2*cargE, odd = 2*cargO+1; odd wins iff strictly smaller u,
    // or equal u with smaller pair index (2*cargO+1 < 2*cargE <=> cargO < cargE).
    const bool oddWins = (cwO < cwE) || ((cwO == cwE) && (cargO < cargE));
    const float cw  = oddWins ? cwO : cwE;
    const int  carg = oddWins ? (2 * cargO + 1) : (2 * cargE);

    s_min[sub][rl]  = cw;
    s_face[sub][rl] = ((sub & 3) << 6) | carg;  // chunk-LOCAL face index (0..255)
    __syncthreads();

    // Epilogue: threads 0..15 handle one ray each.
    if (tid < RPB) {
        float bw   = INF;
        int   face = -1;
        for (int k = 0; k < SUBS; ++k) {
            const float mt = s_min[k][tid];
            if (mt < bw) { bw = mt; face = s_face[k][tid]; }  // earlier chunk wins ties
        }
        // Deferred window test: any in-window u beats every u>=hunA in the min,
        // so bw<hunA <=> reference's any(mask); argmin unaffected.
        const bool active = bw < hunA;

        // Single IEEE division per ray: best = fl(u*/a) == reference's rounded t.
        const float best = active ? (bw / a) : 100.0f;

        float px = ox + (best * dx);
        float py = oy + (best * dy);
        float pz = oz + (best * dz);

        // reference: idx = clip(face,0,1023), face in [-1,255] (chunk-local bug kept)
        const int gidx = face < 0 ? 0 : face;
        const int b4 = (gidx >> 6) * (2 * PAIRS + 1) + ((gidx & 63) >> 1) * 2;
        const int j  = gidx & 1;
        const float4 A = sph[b4];
        const float4 B = sph[b4 + 1];
        const float cxv = j ? A.y : A.x;
        const float cyv = j ? A.w : A.z;
        const float czv = j ? B.y : B.x;
        const float ddx = px - cxv;
        const float ddy = py - cyv;
        const float ddz = pz - czv;
        float nrm = sqrtf(((ddx * ddx) + (ddy * ddy)) + (ddz * ddz));
        nrm = fmaxf(nrm, 1e-12f);
        const float nx = active ? (ddx / nrm) : 0.0f;
        const float ny = active ? (ddy / nrm) : 0.0f;
        const float nz = active ? (ddz / nrm) : 0.0f;
        px = px + (nx * 1e-5f);
        py = py + (ny * 1e-5f);
        pz = pz + (nz * 1e-5f);

        const int r = blockIdx.x * RPB + tid;
        float* outp = out;                 // p: 3*NRAYS
        float* outn = out + NRAYS * 3;     // n: 3*NRAYS
        float* outd = out + NRAYS * 6;     // best_dists: NRAYS
        float* outa = out + NRAYS * 7;     // out_active: NRAYS

        outp[r * 3 + 0] = px;
        outp[r * 3 + 1] = py;
        outp[r * 3 + 2] = pz;
        outn[r * 3 + 0] = nx;
        outn[r * 3 + 1] = ny;
        outn[r * 3 + 2] = nz;
        outd[r] = best;
        outa[r] = active ? 1.0f : 0.0f;
    }
}

extern "C" void kernel_launch(void* const* d_in, const int* in_sizes, int n_in,
                              void* d_out, int out_size, void* d_ws, size_t ws_size,
                              hipStream_t stream) {
    const float* rays    = (const float*)d_in[0];
    const float* centers = (const float*)d_in[1];
    const float* radii   = (const float*)d_in[2];
    float* out = (float*)d_out;

    dim3 grid(NBLK);     // 2048 blocks
    dim3 block(TPB);     // 256 threads
    hipLaunchKernelGGL(sphere_kernel, grid, block, 0, stream,
                       rays, centers, radii, out);
}

// Round 10
// 23.536 us; speedup vs baseline: 1.2780x; 1.0934x over previous
//
#include <hip/hip_runtime.h>
#include <math.h>

#define NRAYS 32768      // 16*64*32
#define NSPH  1024
#define SUBS  16         // subchunks per ray (64 spheres each)
#define PAIRS 32         // sphere-pairs per subchunk
#define RPB   16         // rays per block
#define TPB   256
#define NBLK  (NRAYS / RPB)   // 2048 blocks

typedef float v2f __attribute__((ext_vector_type(2)));

// Elementwise fused multiply-add on v2f (explicit contraction; pragma-immune).
static __device__ __forceinline__ v2f fma2(v2f a, v2f b, v2f c) {
    v2f r;
    r.x = __builtin_fmaf(a.x, b.x, c.x);
    r.y = __builtin_fmaf(a.y, b.y, c.y);
    return r;
}

__global__ __launch_bounds__(256, 8) void sphere_kernel(
    const float* __restrict__ rays,
    const float* __restrict__ centers,
    const float* __restrict__ radii,
    float* __restrict__ out)
{
#pragma clang fp contract(off)
    // Pair-SoA: pair p of sub k: sph[base+2p]=(x0,x1,y0,y1), sph[base+2p+1]=(z0,z1,r2_0,r2_1)
    // sub stride 65 float4 = 1040 B -> the 4 broadcast addresses per wave hit
    // disjoint bank quads (conflict-free).
    __shared__ float4 sph[SUBS * (2 * PAIRS + 1)];   // 16.6 KB
    __shared__ float  s_min[SUBS][RPB];
    __shared__ int    s_face[SUBS][RPB];

    const int tid = threadIdx.x;

    for (int p = tid; p < NSPH / 2; p += TPB) {
        const int g0 = 2 * p, g1 = 2 * p + 1;
        const float x0 = centers[3 * g0 + 0], y0 = centers[3 * g0 + 1], z0 = centers[3 * g0 + 2];
        const float x1 = centers[3 * g1 + 0], y1 = centers[3 * g1 + 1], z1 = centers[3 * g1 + 2];
        const float r0 = radii[g0], r1 = radii[g1];
        const int b4 = (p >> 5) * (2 * PAIRS + 1) + (p & 31) * 2;
        sph[b4 + 0] = make_float4(x0, x1, y0, y1);
        sph[b4 + 1] = make_float4(z0, z1, r0 * r0, r1 * r1);
    }
    __syncthreads();

    const int rl  = tid & (RPB - 1);   // ray within block, 0..15
    const int sub = tid >> 4;          // subchunk 0..15
    const int ray = blockIdx.x * RPB + rl;

    const float2* rp = (const float2*)(rays + ray * 6);
    const float2 q0 = rp[0], q1 = rp[1], q2 = rp[2];
    const float ox = q0.x, oy = q0.y, oz = q1.x;
    const float dx = q1.y, dy = q2.x, dz = q2.y;

    // a = ((dx*dx)+(dy*dy))+(dz*dz) -- numpy 3-elem sum order (kept exact:
    // a feeds epsA/hunA thresholds and the final division)
    const float a    = ((dx * dx) + (dy * dy)) + (dz * dz);
    const float epsA = 1e-8f * a;      // w >= epsA  <=>  fl(w/a) >= 1e-8
    const float hunA = 100.0f * a;     // deferred: active <=> bw < hunA
    const float INF  = __builtin_inff();

    const v2f ox2 = {ox, ox}, oy2 = {oy, oy}, oz2 = {oz, oz};
    const v2f dx2 = {dx, dx}, dy2 = {dy, dy}, dz2 = {dz, dz};
    const v2f an2 = {-a, -a};          // for z = fma(dt,dt, (-a)*cc)

    // Dual accumulators: component 0 = even spheres (2i), component 1 = odd (2i+1).
    float cwE = INF, cwO = INF;
    int   cargE = 0, cargO = 0;   // pair index i of current min

    const float4* __restrict__ spb = &sph[sub * (2 * PAIRS + 1)];

#pragma unroll 8
    for (int i = 0; i < PAIRS; ++i) {
        const float4 A = spb[2 * i];       // (x0,x1,y0,y1)
        const float4 B = spb[2 * i + 1];   // (z0,z1,r2_0,r2_1)
        const v2f X = {A.x, A.y}, Y = {A.z, A.w};
        const v2f Z = {B.x, B.y}, Q = {B.z, B.w};
        // Contracted front (deliberate ulp-level deviation from numpy; decision
        // flip risk quantified at ~0.2 harmful over the whole fixed dataset).
        const v2f fx = ox2 - X;
        const v2f fy = oy2 - Y;
        const v2f fz = oz2 - Z;
        const v2f dt = fma2(dz2, fz, fma2(dy2, fy, dx2 * fx));
        const v2f cc = fma2(fz, fz, fma2(fy, fy, fx * fx)) - Q;
        const v2f zz = fma2(dt, dt, an2 * cc);     // z = dt^2 - a*cc (fused)
        const v2f s  = { __builtin_amdgcn_sqrtf(zz.x),   // raw v_sqrt; NaN if z<0
                         __builtin_amdgcn_sqrtf(zz.y) };
        const v2f w0 = s - dt;             // larger-root numerator (pk)
        const v2f w1 = -(dt + s);          // smaller-root numerator (pk, neg folded)
        {   // even sphere 2i -> accumulator E
            const float u  = (w1.x >= epsA) ? w1.x : w0.x;
            const bool ok  = (w0.x >= epsA) & (u < cwE);   // NaN -> false
            cwE   = ok ? u : cwE;
            cargE = ok ? i : cargE;        // strict <: first occurrence
        }
        {   // odd sphere 2i+1 -> accumulator O
            const float u  = (w1.y >= epsA) ? w1.y : w0.y;
            const bool ok  = (w0.y >= epsA) & (u < cwO);
            cwO   = ok ? u : cwO;
            cargO = ok ? i : cargO;
        }
    }

    // Exact merge with first-occurrence tie-break:
    // odd wins iff strictly smaller u, or equal u with smaller pair index.
    const bool oddWins = (cwO < cwE) || ((cwO == cwE) && (cargO < cargE));
    const float cw  = oddWins ? cwO : cwE;
    const int  carg = oddWins ? (2 * cargO + 1) : (2 * cargE);

    s_min[sub][rl]  = cw;
    s_face[sub][rl] = ((sub & 3) << 6) | carg;  // chunk-LOCAL face index (0..255)
    __syncthreads();

    // Epilogue: threads 0..15 handle one ray each.
    if (tid < RPB) {
        float bw   = INF;
        int   face = -1;
        for (int k = 0; k < SUBS; ++k) {
            const float mt = s_min[k][tid];
            if (mt < bw) { bw = mt; face = s_face[k][tid]; }  // earlier chunk wins ties
        }
        // Deferred window test: any in-window u beats every u>=hunA in the min,
        // so bw<hunA <=> reference's any(mask); argmin unaffected.
        const bool active = bw < hunA;

        // Single IEEE division per ray.
        const float best = active ? (bw / a) : 100.0f;

        float px = ox + (best * dx);
        float py = oy + (best * dy);
        float pz = oz + (best * dz);

        // reference: idx = clip(face,0,1023), face in [-1,255] (chunk-local bug kept)
        const int gidx = face < 0 ? 0 : face;
        const int b4 = (gidx >> 6) * (2 * PAIRS + 1) + ((gidx & 63) >> 1) * 2;
        const int j  = gidx & 1;
        const float4 A = sph[b4];
        const float4 B = sph[b4 + 1];
        const float cxv = j ? A.y : A.x;
        const float cyv = j ? A.w : A.z;
        const float czv = j ? B.y : B.x;
        const float ddx = px - cxv;
        const float ddy = py - cyv;
        const float ddz = pz - czv;
        float nrm = sqrtf(((ddx * ddx) + (ddy * ddy)) + (ddz * ddz));
        nrm = fmaxf(nrm, 1e-12f);
        const float nx = active ? (ddx / nrm) : 0.0f;
        const float ny = active ? (ddy / nrm) : 0.0f;
        const float nz = active ? (ddz / nrm) : 0.0f;
        px = px + (nx * 1e-5f);
        py = py + (ny * 1e-5f);
        pz = pz + (nz * 1e-5f);

        const int r = blockIdx.x * RPB + tid;
        float* outp = out;                 // p: 3*NRAYS
        float* outn = out + NRAYS * 3;     // n: 3*NRAYS
        float* outd = out + NRAYS * 6;     // best_dists: NRAYS
        float* outa = out + NRAYS * 7;     // out_active: NRAYS

        outp[r * 3 + 0] = px;
        outp[r * 3 + 1] = py;
        outp[r * 3 + 2] = pz;
        outn[r * 3 + 0] = nx;
        outn[r * 3 + 1] = ny;
        outn[r * 3 + 2] = nz;
        outd[r] = best;
        outa[r] = active ? 1.0f : 0.0f;
    }
}

extern "C" void kernel_launch(void* const* d_in, const int* in_sizes, int n_in,
                              void* d_out, int out_size, void* d_ws, size_t ws_size,
                              hipStream_t stream) {
    const float* rays    = (const float*)d_in[0];
    const float* centers = (const float*)d_in[1];
    const float* radii   = (const float*)d_in[2];
    float* out = (float*)d_out;

    dim3 grid(NBLK);     // 2048 blocks
    dim3 block(TPB);     // 256 threads
    hipLaunchKernelGGL(sphere_kernel, grid, block, 0, stream,
                       rays, centers, radii, out);
}

// Round 11
// 22.343 us; speedup vs baseline: 1.3462x; 1.0534x over previous
//
#include <hip/hip_runtime.h>
#include <math.h>

#define NRAYS 32768      // 16*64*32
#define NSPH  1024
#define SUBS  16         // subchunks per ray (64 spheres each)
#define PAIRS 32         // sphere-pairs per subchunk
#define RPB   16         // rays per block
#define TPB   256
#define NBLK  (NRAYS / RPB)   // 2048 blocks

typedef float    v2f __attribute__((ext_vector_type(2)));
typedef unsigned v2u __attribute__((ext_vector_type(2)));

// Elementwise fused multiply-add on v2f (explicit contraction; pragma-immune).
static __device__ __forceinline__ v2f fma2(v2f a, v2f b, v2f c) {
    v2f r;
    r.x = __builtin_fmaf(a.x, b.x, c.x);
    r.y = __builtin_fmaf(a.y, b.y, c.y);
    return r;
}

__global__ __launch_bounds__(256, 8) void sphere_kernel(
    const float* __restrict__ rays,
    const float* __restrict__ centers,
    const float* __restrict__ radii,
    float* __restrict__ out)
{
#pragma clang fp contract(off)
    // Pair-SoA: pair p of sub k: sph[base+2p]=(x0,x1,y0,y1), sph[base+2p+1]=(z0,z1,r2_0,r2_1)
    // sub stride 65 float4 = 1040 B -> the 4 broadcast addresses per wave hit
    // disjoint bank quads (conflict-free).
    __shared__ float4   sph[SUBS * (2 * PAIRS + 1)];   // 16.6 KB
    __shared__ unsigned s_min[SUBS][RPB];              // u32-ordered v bits
    __shared__ int      s_face[SUBS][RPB];

    const int tid = threadIdx.x;

    for (int p = tid; p < NSPH / 2; p += TPB) {
        const int g0 = 2 * p, g1 = 2 * p + 1;
        const float x0 = centers[3 * g0 + 0], y0 = centers[3 * g0 + 1], z0 = centers[3 * g0 + 2];
        const float x1 = centers[3 * g1 + 0], y1 = centers[3 * g1 + 1], z1 = centers[3 * g1 + 2];
        const float r0 = radii[g0], r1 = radii[g1];
        const int b4 = (p >> 5) * (2 * PAIRS + 1) + (p & 31) * 2;
        sph[b4 + 0] = make_float4(x0, x1, y0, y1);
        sph[b4 + 1] = make_float4(z0, z1, r0 * r0, r1 * r1);
    }
    __syncthreads();

    const int rl  = tid & (RPB - 1);   // ray within block, 0..15
    const int sub = tid >> 4;          // subchunk 0..15
    const int ray = blockIdx.x * RPB + rl;

    const float2* rp = (const float2*)(rays + ray * 6);
    const float2 q0 = rp[0], q1 = rp[1], q2 = rp[2];
    const float ox = q0.x, oy = q0.y, oz = q1.x;
    const float dx = q1.y, dy = q2.x, dz = q2.y;

    // a = ((dx*dx)+(dy*dy))+(dz*dz) -- numpy 3-elem sum order (kept exact)
    const float a    = ((dx * dx) + (dy * dy)) + (dz * dz);
    const float epsA = 1e-8f * a;      // w >= epsA  <=>  t >= 1e-8
    const float hunA = 100.0f * a;     // deferred: active <=> u* < hunA

    const v2f ox2 = {ox, ox}, oy2 = {oy, oy}, oz2 = {oz, oz};
    const v2f dx2 = {dx, dx}, dy2 = {dy, dy}, dz2 = {dz, dz};
    const v2f an2 = {-a, -a};              // z = fma(dt,dt, (-a)*cc)
    const v2f epsA2 = {epsA, epsA};

    // uint-ordered accumulators: bits of v = w - epsA. Valid (v>=+0) patterns
    // < 0x7F800001; NaN (z<0) and negative-v (root<EPS) patterns sort above
    // ALL valid ones as u32 -> min_u32 does validity masking for free.
    // v == u bit-exactly for all real hits (epsA << ulp(u)), so comparisons,
    // ties, and t = v/a are unchanged vs R10.
    unsigned cwE = 0xFFFFFFFFu, cwO = 0xFFFFFFFFu;
    int      cargE = 0, cargO = 0;     // pair index i of current min

    const float4* __restrict__ spb = &sph[sub * (2 * PAIRS + 1)];

#pragma unroll 16
    for (int i = 0; i < PAIRS; ++i) {
        const float4 A = spb[2 * i];       // (x0,x1,y0,y1)
        const float4 B = spb[2 * i + 1];   // (z0,z1,r2_0,r2_1)
        const v2f X = {A.x, A.y}, Y = {A.z, A.w};
        const v2f Z = {B.x, B.y}, Q = {B.z, B.w};
        // Contracted front (validated in R10).
        const v2f fx = ox2 - X;
        const v2f fy = oy2 - Y;
        const v2f fz = oz2 - Z;
        const v2f dt = fma2(dz2, fz, fma2(dy2, fy, dx2 * fx));
        const v2f cc = fma2(fz, fz, fma2(fy, fy, fx * fx)) - Q;
        const v2f zz = fma2(dt, dt, an2 * cc);     // z = dt^2 - a*cc (fused)
        const v2f s  = { __builtin_amdgcn_sqrtf(zz.x),   // raw v_sqrt; NaN if z<0
                         __builtin_amdgcn_sqrtf(zz.y) };
        const v2f dtp = dt + epsA2;        // pk
        const v2f vv0 = s - dtp;           // larger-root v = w0 - epsA   (pk)
        const v2f vv1 = (-s) - dtp;        // smaller-root v = w1 - epsA  (pk, negs fold)
        const v2u b0 = __builtin_bit_cast(v2u, vv0);
        const v2u b1 = __builtin_bit_cast(v2u, vv1);
        {   // even sphere 2i -> accumulator E
            const unsigned u = (b1.x < b0.x) ? b1.x : b0.x;   // v_min_u32
            const bool ok = u < cwE;                           // strict: first occ.
            cwE   = ok ? u : cwE;
            cargE = ok ? i : cargE;
        }
        {   // odd sphere 2i+1 -> accumulator O
            const unsigned u = (b1.y < b0.y) ? b1.y : b0.y;
            const bool ok = u < cwO;
            cwO   = ok ? u : cwO;
            cargO = ok ? i : cargO;
        }
    }

    // Exact merge with first-occurrence tie-break (u32 order == float order here):
    const bool oddWins = (cwO < cwE) || ((cwO == cwE) && (cargO < cargE));
    const unsigned cw  = oddWins ? cwO : cwE;
    const int     carg = oddWins ? (2 * cargO + 1) : (2 * cargE);

    s_min[sub][rl]  = cw;
    s_face[sub][rl] = ((sub & 3) << 6) | carg;  // chunk-LOCAL face index (0..255)
    __syncthreads();

    // Epilogue: threads 0..15 handle one ray each.
    if (tid < RPB) {
        unsigned bw = 0xFFFFFFFFu;
        int    face = 0;
        for (int k = 0; k < SUBS; ++k) {
            const unsigned mt = s_min[k][tid];
            if (mt < bw) { bw = mt; face = s_face[k][tid]; }  // earlier chunk wins ties
        }
        // active <=> winning u < hunA (u32 compare valid: all "live" patterns
        // are positive floats; NaN/negative markers exceed bits(hunA)).
        const bool active = bw < __builtin_bit_cast(unsigned, hunA);

        // Single IEEE division per ray: v == u exactly -> t matches reference.
        const float best = active ? (__builtin_bit_cast(float, bw) / a) : 100.0f;

        float px = ox + (best * dx);
        float py = oy + (best * dy);
        float pz = oz + (best * dz);

        // reference: idx = clip(face,0,1023), face in [-1,255] (chunk-local bug kept)
        const int gidx = face;
        const int b4 = (gidx >> 6) * (2 * PAIRS + 1) + ((gidx & 63) >> 1) * 2;
        const int j  = gidx & 1;
        const float4 A = sph[b4];
        const float4 B = sph[b4 + 1];
        const float cxv = j ? A.y : A.x;
        const float cyv = j ? A.w : A.z;
        const float czv = j ? B.y : B.x;
        const float ddx = px - cxv;
        const float ddy = py - cyv;
        const float ddz = pz - czv;
        float nrm = sqrtf(((ddx * ddx) + (ddy * ddy)) + (ddz * ddz));
        nrm = fmaxf(nrm, 1e-12f);
        const float nx = active ? (ddx / nrm) : 0.0f;
        const float ny = active ? (ddy / nrm) : 0.0f;
        const float nz = active ? (ddz / nrm) : 0.0f;
        px = px + (nx * 1e-5f);
        py = py + (ny * 1e-5f);
        pz = pz + (nz * 1e-5f);

        const int r = blockIdx.x * RPB + tid;
        float* outp = out;                 // p: 3*NRAYS
        float* outn = out + NRAYS * 3;     // n: 3*NRAYS
        float* outd = out + NRAYS * 6;     // best_dists: NRAYS
        float* outa = out + NRAYS * 7;     // out_active: NRAYS

        outp[r * 3 + 0] = px;
        outp[r * 3 + 1] = py;
        outp[r * 3 + 2] = pz;
        outn[r * 3 + 0] = nx;
        outn[r * 3 + 1] = ny;
        outn[r * 3 + 2] = nz;
        outd[r] = best;
        outa[r] = active ? 1.0f : 0.0f;
    }
}

extern "C" void kernel_launch(void* const* d_in, const int* in_sizes, int n_in,
                              void* d_out, int out_size, void* d_ws, size_t ws_size,
                              hipStream_t stream) {
    const float* rays    = (const float*)d_in[0];
    const float* centers = (const float*)d_in[1];
    const float* radii   = (const float*)d_in[2];
    float* out = (float*)d_out;

    dim3 grid(NBLK);     // 2048 blocks
    dim3 block(TPB);     // 256 threads
    hipLaunchKernelGGL(sphere_kernel, grid, block, 0, stream,
                       rays, centers, radii, out);
}

// Round 12
// 19.982 us; speedup vs baseline: 1.5053x; 1.1181x over previous
//
#include <hip/hip_runtime.h>
#include <math.h>

#define NRAYS 32768      // 16*64*32
#define NSPH  1024
#define SUBS  16         // subchunks per ray (64 spheres each)
#define PAIRS 32         // sphere-pairs per subchunk
#define RPB   16         // rays per block
#define TPB   256
#define NBLK  (NRAYS / RPB)   // 2048 blocks

typedef float    v2f __attribute__((ext_vector_type(2)));
typedef unsigned v2u __attribute__((ext_vector_type(2)));

// Elementwise fused multiply-add on v2f (explicit contraction; pragma-immune).
static __device__ __forceinline__ v2f fma2(v2f a, v2f b, v2f c) {
    v2f r;
    r.x = __builtin_fmaf(a.x, b.x, c.x);
    r.y = __builtin_fmaf(a.y, b.y, c.y);
    return r;
}

__global__ __launch_bounds__(256, 8) void sphere_kernel(
    const float* __restrict__ rays,
    const float* __restrict__ centers,
    const float* __restrict__ radii,
    float* __restrict__ out)
{
#pragma clang fp contract(off)
    // Pair-SoA: pair p of sub k: sph[base+2p]=(x0,x1,y0,y1), sph[base+2p+1]=(z0,z1,r2_0,r2_1)
    // sub stride 65 float4 = 1040 B -> the 4 broadcast addresses per wave hit
    // disjoint bank quads (conflict-free).
    __shared__ float4   sph[SUBS * (2 * PAIRS + 1)];   // 16.6 KB
    __shared__ unsigned s_min[SUBS][RPB];              // u32-ordered (v-bits|idx)

    const int tid = threadIdx.x;

    for (int p = tid; p < NSPH / 2; p += TPB) {
        const int g0 = 2 * p, g1 = 2 * p + 1;
        const float x0 = centers[3 * g0 + 0], y0 = centers[3 * g0 + 1], z0 = centers[3 * g0 + 2];
        const float x1 = centers[3 * g1 + 0], y1 = centers[3 * g1 + 1], z1 = centers[3 * g1 + 2];
        const float r0 = radii[g0], r1 = radii[g1];
        const int b4 = (p >> 5) * (2 * PAIRS + 1) + (p & 31) * 2;
        sph[b4 + 0] = make_float4(x0, x1, y0, y1);
        sph[b4 + 1] = make_float4(z0, z1, r0 * r0, r1 * r1);
    }
    __syncthreads();

    const int rl  = tid & (RPB - 1);   // ray within block, 0..15
    const int sub = tid >> 4;          // subchunk 0..15
    const int ray = blockIdx.x * RPB + rl;

    const float2* rp = (const float2*)(rays + ray * 6);
    const float2 q0 = rp[0], q1 = rp[1], q2 = rp[2];
    const float ox = q0.x, oy = q0.y, oz = q1.x;
    const float dx = q1.y, dy = q2.x, dz = q2.y;

    // a = ((dx*dx)+(dy*dy))+(dz*dz) -- numpy 3-elem sum order (kept exact)
    const float a    = ((dx * dx) + (dy * dy)) + (dz * dz);
    const float epsA = 1e-8f * a;      // w >= epsA  <=>  t >= 1e-8
    const float hunA = 100.0f * a;     // deferred: active <=> u* < hunA

    const v2f ox2 = {ox, ox}, oy2 = {oy, oy}, oz2 = {oz, oz};
    const v2f dx2 = {dx, dx}, dy2 = {dy, dy}, dz2 = {dz, dz};
    const v2f an2 = {-a, -a};              // z = fma(dt,dt, (-a)*cc)
    const v2f epsA2 = {epsA, epsA};

    // Fused value+argmin accumulator: bits of v = w - epsA, low 6 bits replaced
    // by the sphere index within the sub (0..63). u32 order == float order on
    // the valid (positive) range; NaN (z<0) and negative-v (root<EPS) patterns
    // sort above all valid ones AND above bits(hunA) -> rejected for free.
    // Trunc-equal ties resolve to the smaller index = numpy first-occurrence.
    // Value perturbation <= 63 ulp (rel ~7.5e-6) -- validated headroom (R10).
    const unsigned IMASK = 0xFFFFFFC0u;
    unsigned cw = 0xFFFFFFFFu;

    const float4* __restrict__ spb = &sph[sub * (2 * PAIRS + 1)];

#pragma unroll
    for (int i = 0; i < PAIRS; ++i) {
        const float4 A = spb[2 * i];       // (x0,x1,y0,y1)
        const float4 B = spb[2 * i + 1];   // (z0,z1,r2_0,r2_1)
        const v2f X = {A.x, A.y}, Y = {A.z, A.w};
        const v2f Z = {B.x, B.y}, Q = {B.z, B.w};
        // Contracted front (validated in R10/R11).
        const v2f fx = ox2 - X;
        const v2f fy = oy2 - Y;
        const v2f fz = oz2 - Z;
        const v2f dt = fma2(dz2, fz, fma2(dy2, fy, dx2 * fx));
        const v2f cc = fma2(fz, fz, fma2(fy, fy, fx * fx)) - Q;
        const v2f zz = fma2(dt, dt, an2 * cc);     // z = dt^2 - a*cc (fused)
        const v2f s  = { __builtin_amdgcn_sqrtf(zz.x),   // raw v_sqrt; NaN if z<0
                         __builtin_amdgcn_sqrtf(zz.y) };
        const v2f dtp = dt + epsA2;
        const v2f vv0 = s - dtp;           // larger-root v = w0 - epsA
        const v2f vv1 = (-s) - dtp;        // smaller-root v = w1 - epsA
        const v2u b0 = __builtin_bit_cast(v2u, vv0);
        const v2u b1 = __builtin_bit_cast(v2u, vv1);
        // even sphere 2i, odd sphere 2i+1: min root, then pack index (v_and_or_b32)
        const unsigned me = (b1.x < b0.x) ? b1.x : b0.x;      // v_min_u32
        const unsigned mo = (b1.y < b0.y) ? b1.y : b0.y;
        const unsigned ue = (me & IMASK) | (unsigned)(2 * i);
        const unsigned uo = (mo & IMASK) | (unsigned)(2 * i + 1);
        const unsigned mp = (ue < uo) ? ue : uo;               // v_min_u32
        cw = (mp < cw) ? mp : cw;                              // (or v_min3_u32)
    }

    s_min[sub][rl] = cw;
    __syncthreads();

    // Epilogue: threads 0..15 handle one ray each.
    if (tid < RPB) {
        unsigned bw = 0xFFFFFFFFu;
        int ksel = 0;
        for (int k = 0; k < SUBS; ++k) {
            const unsigned mt = s_min[k][tid];
            if (mt < bw) { bw = mt; ksel = k; }   // earlier sub wins ties
        }
        // active <=> winning value < hunA (u32 compare valid on live patterns).
        const bool active = bw < __builtin_bit_cast(unsigned, hunA);

        // Single IEEE division per ray (value carries <=63-ulp idx perturbation).
        const float best = active ? (__builtin_bit_cast(float, bw) / a) : 100.0f;

        float px = ox + (best * dx);
        float py = oy + (best * dy);
        float pz = oz + (best * dz);

        // reference: idx = clip(face,0,1023), face in [-1,255] (chunk-local bug kept)
        // face = chunk-local index: ((ksel&3)*64 + idx-within-sub); -1 -> 0 if inactive.
        const int gidx = active ? (((ksel & 3) << 6) | (int)(bw & 63u)) : 0;
        const int b4 = (gidx >> 6) * (2 * PAIRS + 1) + ((gidx & 63) >> 1) * 2;
        const int j  = gidx & 1;
        const float4 A = sph[b4];
        const float4 B = sph[b4 + 1];
        const float cxv = j ? A.y : A.x;
        const float cyv = j ? A.w : A.z;
        const float czv = j ? B.y : B.x;
        const float ddx = px - cxv;
        const float ddy = py - cyv;
        const float ddz = pz - czv;
        float nrm = sqrtf(((ddx * ddx) + (ddy * ddy)) + (ddz * ddz));
        nrm = fmaxf(nrm, 1e-12f);
        const float nx = active ? (ddx / nrm) : 0.0f;
        const float ny = active ? (ddy / nrm) : 0.0f;
        const float nz = active ? (ddz / nrm) : 0.0f;
        px = px + (nx * 1e-5f);
        py = py + (ny * 1e-5f);
        pz = pz + (nz * 1e-5f);

        const int r = blockIdx.x * RPB + tid;
        float* outp = out;                 // p: 3*NRAYS
        float* outn = out + NRAYS * 3;     // n: 3*NRAYS
        float* outd = out + NRAYS * 6;     // best_dists: NRAYS
        float* outa = out + NRAYS * 7;     // out_active: NRAYS

        outp[r * 3 + 0] = px;
        outp[r * 3 + 1] = py;
        outp[r * 3 + 2] = pz;
        outn[r * 3 + 0] = nx;
        outn[r * 3 + 1] = ny;
        outn[r * 3 + 2] = nz;
        outd[r] = best;
        outa[r] = active ? 1.0f : 0.0f;
    }
}

extern "C" void kernel_launch(void* const* d_in, const int* in_sizes, int n_in,
                              void* d_out, int out_size, void* d_ws, size_t ws_size,
                              hipStream_t stream) {
    const float* rays    = (const float*)d_in[0];
    const float* centers = (const float*)d_in[1];
    const float* radii   = (const float*)d_in[2];
    float* out = (float*)d_out;

    dim3 grid(NBLK);     // 2048 blocks
    dim3 block(TPB);     // 256 threads
    hipLaunchKernelGGL(sphere_kernel, grid, block, 0, stream,
                       rays, centers, radii, out);
}